// Round 4
// baseline (248.910 us; speedup 1.0000x reference)
//
#include <hip/hip_runtime.h>
#include <stdint.h>

#define GMAX 128
#define TK 128            // FG_ROIS_PER_IMAGE = BG_ROIS_PER_IMAGE = 128
#define NBINS 4096
#define CAND_MAX 4096
#define NUM_CLASSES 21
#define GRID 256          // 1 block/CU -> all co-resident (required for grid barrier)
#define BLOCK 1024
#define EPT_MAX 8

// ---------------------------------------------------------------------------
// JAX threefry2x32 block cipher (key = [hi32(seed), lo32(seed)] = [0, 42])
// ---------------------------------------------------------------------------
__device__ __forceinline__ void threefry2x32(uint32_t k0, uint32_t k1,
                                             uint32_t& x0, uint32_t& x1) {
  uint32_t ks0 = k0, ks1 = k1, ks2 = k0 ^ k1 ^ 0x1BD11BDAu;
  x0 += ks0; x1 += ks1;
#define TF_ROUND(r) { x0 += x1; x1 = (x1 << (r)) | (x1 >> (32 - (r))); x1 ^= x0; }
  TF_ROUND(13) TF_ROUND(15) TF_ROUND(26) TF_ROUND(6)
  x0 += ks1; x1 += ks2 + 1u;
  TF_ROUND(17) TF_ROUND(29) TF_ROUND(16) TF_ROUND(24)
  x0 += ks2; x1 += ks0 + 2u;
  TF_ROUND(13) TF_ROUND(15) TF_ROUND(26) TF_ROUND(6)
  x0 += ks0; x1 += ks1 + 3u;
  TF_ROUND(17) TF_ROUND(29) TF_ROUND(16) TF_ROUND(24)
  x0 += ks1; x1 += ks2 + 4u;
  TF_ROUND(13) TF_ROUND(15) TF_ROUND(26) TF_ROUND(6)
  x0 += ks2; x1 += ks0 + 5u;
#undef TF_ROUND
}

// ---------------------------------------------------------------------------
// Device-scope grid barrier. Safe because grid==GRID blocks are all resident
// (1 block/CU: 16 waves, ~50KB LDS). Release: per-thread __threadfence before
// the counter add; acquire: agent-scope atomic load (invalidates L1).
// ---------------------------------------------------------------------------
__device__ __forceinline__ void grid_barrier(int* ctr, int target) {
  __threadfence();
  __syncthreads();
  if (threadIdx.x == 0) {
    __hip_atomic_fetch_add(ctr, 1, __ATOMIC_ACQ_REL, __HIP_MEMORY_SCOPE_AGENT);
    while (__hip_atomic_load(ctr, __ATOMIC_ACQUIRE, __HIP_MEMORY_SCOPE_AGENT) < target) {
      __builtin_amdgcn_s_sleep(8);
    }
  }
  __syncthreads();
}

// ---------------------------------------------------------------------------
// Fused pipeline:
//  A: per-ROI max-IoU/argmax (exact __f*_rn arithmetic), partitionable
//     threefry u, packed score word [ubits23<<9 | gt(7b)<<2 | fg<<1 | bg],
//     global histogram (4096 bins/mask) of ubits top-12 bits.
//  barrier
//  B: every block redundantly computes exact per-mask threshold bin Bth
//     (count(bin>=Bth) >= TK) via packed fg|bg uint64 suffix scan.
//  C: compact candidates (scores still in registers) -> global lists.
//  barrier
//  D: block 0: bitonic sort (key ((ubits+1)<<32)|~i == XLA stable top_k with
//     where(mask,u,-1.0) padding), gather rois/labels/class-scattered targets.
// meta[0]=cnt_fg meta[1]=cnt_bg meta[2]=sync_counter  (memset to 0 pre-launch)
// ---------------------------------------------------------------------------
__global__ void __launch_bounds__(BLOCK)
fused_kernel(const float* __restrict__ all_rois,
             const float* __restrict__ gt_boxes,
             const int* __restrict__ gt_labels,
             int* __restrict__ meta,
             uint32_t* __restrict__ hist,
             uint32_t* __restrict__ score,
             uint64_t* __restrict__ cand_g,
             float* __restrict__ out,
             int N, int M, int G) {
  __shared__ float sgx1[GMAX], sgy1[GMAX], sgx2[GMAX], sgy2[GMAX], sga[GMAX];
  __shared__ uint64_t gs[BLOCK];
  __shared__ int s_jstar[2], s_bth[2];
  __shared__ uint64_t cand[CAND_MAX];
  __shared__ int keep[2 * TK];
  __shared__ int fgvalid[TK];
  __shared__ float s_tx[2 * TK], s_ty[2 * TK], s_tw[2 * TK], s_th[2 * TK];
  __shared__ int s_label[2 * TK];

  const int t = threadIdx.x;
  const int stride = GRID * BLOCK;

  if (t < G) {
    float x1 = gt_boxes[t * 4 + 0];
    float y1 = gt_boxes[t * 4 + 1];
    float x2 = gt_boxes[t * 4 + 2];
    float y2 = gt_boxes[t * 4 + 3];
    sgx1[t] = x1; sgy1[t] = y1; sgx2[t] = x2; sgy2[t] = y2;
    sga[t] = __fmul_rn(__fadd_rn(__fsub_rn(x2, x1), 1.0f),
                       __fadd_rn(__fsub_rn(y2, y1), 1.0f));
  }
  __syncthreads();

  // ----- Phase A: score -----
  uint32_t sv[EPT_MAX];
  for (int i = blockIdx.x * BLOCK + t, e = 0; i < M && e < EPT_MAX;
       i += stride, ++e) {
    float bx1, by1, bx2, by2;
    if (i < N) {
      bx1 = all_rois[(size_t)i * 5 + 1];
      by1 = all_rois[(size_t)i * 5 + 2];
      bx2 = all_rois[(size_t)i * 5 + 3];
      by2 = all_rois[(size_t)i * 5 + 4];
    } else {
      int g = i - N;
      bx1 = sgx1[g]; by1 = sgy1[g]; bx2 = sgx2[g]; by2 = sgy2[g];
    }
    const float area = __fmul_rn(__fadd_rn(__fsub_rn(bx2, bx1), 1.0f),
                                 __fadd_rn(__fsub_rn(by2, by1), 1.0f));
    float best = -1.0f;
    int bi = 0;
    for (int g = 0; g < G; ++g) {
      float ix1 = fmaxf(bx1, sgx1[g]);
      float iy1 = fmaxf(by1, sgy1[g]);
      float ix2 = fminf(bx2, sgx2[g]);
      float iy2 = fminf(by2, sgy2[g]);
      float iw = fmaxf(__fadd_rn(__fsub_rn(ix2, ix1), 1.0f), 0.0f);
      float ih = fmaxf(__fadd_rn(__fsub_rn(iy2, iy1), 1.0f), 0.0f);
      float inter = __fmul_rn(iw, ih);
      float uni = __fsub_rn(__fadd_rn(area, sga[g]), inter);
      float ov = __fdiv_rn(inter, uni);             // IEEE-rounded, matches XLA
      if (ov > best) { best = ov; bi = g; }         // first-max == jnp.argmax
    }
    uint32_t cx0 = 0u, cx1 = (uint32_t)i;           // partitionable threefry
    threefry2x32(0u, 42u, cx0, cx1);
    uint32_t ubits = (cx0 ^ cx1) >> 9;
    uint32_t fg = (best >= 0.5f) ? 1u : 0u;
    uint32_t bg = (!fg && best >= 0.1f) ? 1u : 0u;
    uint32_t s = (ubits << 9) | ((uint32_t)bi << 2) | (fg << 1) | bg;
    sv[e] = s;
    score[i] = s;
    if (fg)      atomicAdd(&hist[ubits >> 11], 1u);
    else if (bg) atomicAdd(&hist[NBINS + (ubits >> 11)], 1u);
  }

  grid_barrier(&meta[2], GRID);

  // ----- Phase B: exact threshold (redundant per block) -----
  {
    const int b0 = 4 * t;
    uint64_t acc = 0;
    for (int k = 0; k < 4; ++k)
      acc += ((uint64_t)hist[b0 + k] << 32) | (uint64_t)hist[NBINS + b0 + k];
    gs[t] = acc;
    if (t < 2) s_jstar[t] = -1;
    __syncthreads();
    for (int d = 1; d < BLOCK; d <<= 1) {
      uint64_t add = (t + d < BLOCK) ? gs[t + d] : 0ull;
      __syncthreads();
      gs[t] += add;
      __syncthreads();
    }
    uint32_t vfg = (uint32_t)(gs[t] >> 32);
    uint32_t vbg = (uint32_t)gs[t];
    uint32_t nfg = (t < BLOCK - 1) ? (uint32_t)(gs[t + 1] >> 32) : 0u;
    uint32_t nbg = (t < BLOCK - 1) ? (uint32_t)gs[t + 1] : 0u;
    if (vfg >= (uint32_t)TK && (t == BLOCK - 1 || nfg < (uint32_t)TK)) s_jstar[0] = t;
    if (vbg >= (uint32_t)TK && (t == BLOCK - 1 || nbg < (uint32_t)TK)) s_jstar[1] = t;
    __syncthreads();
    if (t == 0) {
      for (int m = 0; m < 2; ++m) {
        int j = s_jstar[m], B = -1;
        if (j >= 0) {
          uint32_t base = 0;
          if (j < BLOCK - 1)
            base = (m == 0) ? (uint32_t)(gs[j + 1] >> 32) : (uint32_t)gs[j + 1];
          const uint32_t* h = hist + m * NBINS;
          B = 4 * j;
          for (int b = 4 * j + 3; b >= 4 * j; --b) {
            base += h[b];
            if (base >= (uint32_t)TK) { B = b; break; }
          }
        }
        s_bth[m] = B;
      }
    }
    __syncthreads();
  }

  // ----- Phase C: compact (scores in registers) -----
  for (int i = blockIdx.x * BLOCK + t, e = 0; i < M && e < EPT_MAX;
       i += stride, ++e) {
    uint32_t s = sv[e];
    uint32_t mb = s & 3u;
    if (!mb) continue;
    int m = (mb & 2u) ? 0 : 1;
    int B = s_bth[m];
    if (B >= 0 && (int)(s >> 20) < B) continue;
    int p = __hip_atomic_fetch_add(&meta[m], 1, __ATOMIC_RELAXED,
                                   __HIP_MEMORY_SCOPE_AGENT);
    if (p < CAND_MAX)
      cand_g[(size_t)m * CAND_MAX + p] =
          (((uint64_t)((s >> 9) + 1u)) << 32) | (uint64_t)(~(uint32_t)i);
  }

  grid_barrier(&meta[2], 2 * GRID);
  if (blockIdx.x != 0) return;

  // ----- Phase D: block 0 sorts + finalizes -----
  for (int m = 0; m < 2; ++m) {
    int cnt = meta[m]; if (cnt > CAND_MAX) cnt = CAND_MAX;
    const int Bth = s_bth[m];
    int P = TK;
    while (P < cnt) P <<= 1;
    for (int p = t; p < P; p += BLOCK)
      cand[p] = (p < cnt) ? cand_g[(size_t)m * CAND_MAX + p] : 0ull;
    __syncthreads();
    for (int k = 2; k <= P; k <<= 1) {
      for (int j = k >> 1; j > 0; j >>= 1) {
        for (int idx = t; idx < P; idx += BLOCK) {
          int l = idx ^ j;
          if (l > idx) {
            uint64_t a = cand[idx], b = cand[l];
            bool swp = ((idx & k) == 0) ? (a < b) : (a > b);
            if (swp) { cand[idx] = b; cand[l] = a; }
          }
        }
        __syncthreads();
      }
    }
    if (Bth < 0 && t == 0) {        // <TK masked: pad with lowest-index
      int fill = cnt;               // non-masked (JAX -1.0 tie semantics)
      uint32_t mask_bit = (m == 0) ? 2u : 1u;
      for (int i = 0; i < M && fill < TK; ++i)
        if (!(score[i] & mask_bit)) cand[fill++] = (uint64_t)(~(uint32_t)i);
    }
    __syncthreads();
    if (t < TK) {
      uint64_t c = cand[t];
      keep[m * TK + t] = (int)(~(uint32_t)(c & 0xFFFFFFFFull));
      if (m == 0) fgvalid[t] = ((c >> 32) != 0ull) ? 1 : 0;
    }
    __syncthreads();
  }

  const int R = 2 * TK;
  float* rois_out   = out;
  float* labels_out = out + (size_t)R * 5;
  float* bt_out     = out + (size_t)R * 5 + R;

  if (t < R) {
    const int i = keep[t];
    float rimg, rx1, ry1, rx2, ry2;
    if (i < N) {
      rimg = all_rois[(size_t)i * 5 + 0];
      rx1  = all_rois[(size_t)i * 5 + 1];
      ry1  = all_rois[(size_t)i * 5 + 2];
      rx2  = all_rois[(size_t)i * 5 + 3];
      ry2  = all_rois[(size_t)i * 5 + 4];
    } else {
      int g = i - N;
      rimg = 0.0f;
      rx1 = gt_boxes[g * 4 + 0]; ry1 = gt_boxes[g * 4 + 1];
      rx2 = gt_boxes[g * 4 + 2]; ry2 = gt_boxes[g * 4 + 3];
    }
    rois_out[t * 5 + 0] = rimg;
    rois_out[t * 5 + 1] = rx1;
    rois_out[t * 5 + 2] = ry1;
    rois_out[t * 5 + 3] = rx2;
    rois_out[t * 5 + 4] = ry2;

    const int ga = (int)((score[i] >> 2) & 127u);
    int label = (t < TK && fgvalid[t]) ? gt_labels[ga] : 0;
    labels_out[t] = (float)label;
    s_label[t] = label;

    float gx1 = gt_boxes[ga * 4 + 0], gy1 = gt_boxes[ga * 4 + 1];
    float gx2 = gt_boxes[ga * 4 + 2], gy2 = gt_boxes[ga * 4 + 3];
    float ew = rx2 - rx1 + 1.0f, eh = ry2 - ry1 + 1.0f;
    float ecx = rx1 + 0.5f * ew, ecy = ry1 + 0.5f * eh;
    float gw = gx2 - gx1 + 1.0f, gh = gy2 - gy1 + 1.0f;
    float gcx = gx1 + 0.5f * gw, gcy = gy1 + 0.5f * gh;
    s_tx[t] = (gcx - ecx) / ew;
    s_ty[t] = (gcy - ecy) / eh;
    s_tw[t] = logf(gw / ew);
    s_th[t] = logf(gh / eh);
  }
  __syncthreads();

  const int TOT = R * 4 * NUM_CLASSES;
  for (int idx = t; idx < TOT; idx += BLOCK) {
    int r = idx / (4 * NUM_CLASSES);
    int c = idx - r * (4 * NUM_CLASSES);
    int lab = s_label[r];
    float v = 0.0f;
    if (lab > 0 && (c >> 2) == lab) {
      int cc = c & 3;
      v = (cc == 0) ? s_tx[r] : (cc == 1) ? s_ty[r] : (cc == 2) ? s_tw[r] : s_th[r];
    }
    bt_out[idx] = v;
  }
}

// ---------------------------------------------------------------------------
extern "C" void kernel_launch(void* const* d_in, const int* in_sizes, int n_in,
                              void* d_out, int out_size, void* d_ws, size_t ws_size,
                              hipStream_t stream) {
  const float* all_rois = (const float*)d_in[0];
  const float* gt_boxes = (const float*)d_in[1];
  const int*   gt_labels = (const int*)d_in[2];
  const int N = in_sizes[0] / 5;
  const int G = in_sizes[2];
  const int M = N + G;

  // workspace layout: [meta 256B][hist 32KB][score M*4][cand 64KB]
  char* ws = (char*)d_ws;
  int* meta = (int*)ws;                       // [0]=cnt_fg [1]=cnt_bg [2]=sync
  uint32_t* hist = (uint32_t*)(ws + 256);
  size_t off = 256 + (size_t)2 * NBINS * 4;
  uint32_t* score = (uint32_t*)(ws + off);
  off += (((size_t)M * 4) + 255) & ~(size_t)255;
  uint64_t* cand = (uint64_t*)(ws + off);
  float* out = (float*)d_out;

  hipMemsetAsync(ws, 0, 256 + (size_t)2 * NBINS * 4, stream);
  fused_kernel<<<GRID, BLOCK, 0, stream>>>(all_rois, gt_boxes, gt_labels,
                                           meta, hist, score, cand, out,
                                           N, M, G);
}

// Round 5
// 116.752 us; speedup vs baseline: 2.1320x; 2.1320x over previous
//
#include <hip/hip_runtime.h>
#include <stdint.h>

#define GMAX 128
#define TK 128            // FG_ROIS_PER_IMAGE = BG_ROIS_PER_IMAGE = 128
#define NBINS 4096
#define CAND_MAX 4096
#define NUM_CLASSES 21
#define CBLOCK 1024
#define CBLOCKS 62        // compact grid: 62*1024*4 >= M

// ---------------------------------------------------------------------------
// JAX threefry2x32 block cipher (key = [hi32(seed), lo32(seed)] = [0, 42])
// ---------------------------------------------------------------------------
__device__ __forceinline__ void threefry2x32(uint32_t k0, uint32_t k1,
                                             uint32_t& x0, uint32_t& x1) {
  uint32_t ks0 = k0, ks1 = k1, ks2 = k0 ^ k1 ^ 0x1BD11BDAu;
  x0 += ks0; x1 += ks1;
#define TF_ROUND(r) { x0 += x1; x1 = (x1 << (r)) | (x1 >> (32 - (r))); x1 ^= x0; }
  TF_ROUND(13) TF_ROUND(15) TF_ROUND(26) TF_ROUND(6)
  x0 += ks1; x1 += ks2 + 1u;
  TF_ROUND(17) TF_ROUND(29) TF_ROUND(16) TF_ROUND(24)
  x0 += ks2; x1 += ks0 + 2u;
  TF_ROUND(13) TF_ROUND(15) TF_ROUND(26) TF_ROUND(6)
  x0 += ks0; x1 += ks1 + 3u;
  TF_ROUND(17) TF_ROUND(29) TF_ROUND(16) TF_ROUND(24)
  x0 += ks1; x1 += ks2 + 4u;
  TF_ROUND(13) TF_ROUND(15) TF_ROUND(26) TF_ROUND(6)
  x0 += ks2; x1 += ks0 + 5u;
#undef TF_ROUND
}

// ---------------------------------------------------------------------------
// Kernel 1 (verified r3): per-ROI max-IoU, argmax (first-max), partitionable
// threefry uniform -> packed score [ubits23<<9 | gt(7b)<<2 | fg<<1 | bg]
// + fused global histogram (4096 bins per mask) of ubits top-12 bits.
// ---------------------------------------------------------------------------
__global__ void __launch_bounds__(256)
score_kernel(const float* __restrict__ all_rois,   // [N,5]
             const float* __restrict__ gt_boxes,   // [G,4]
             uint32_t* __restrict__ score,         // [M]
             uint32_t* __restrict__ hist,          // [2*NBINS] fg|bg
             int N, int M, int G) {
  __shared__ float sgx1[GMAX], sgy1[GMAX], sgx2[GMAX], sgy2[GMAX], sga[GMAX];
  const int t = threadIdx.x;
  if (t < G) {
    float x1 = gt_boxes[t * 4 + 0];
    float y1 = gt_boxes[t * 4 + 1];
    float x2 = gt_boxes[t * 4 + 2];
    float y2 = gt_boxes[t * 4 + 3];
    sgx1[t] = x1; sgy1[t] = y1; sgx2[t] = x2; sgy2[t] = y2;
    sga[t] = __fmul_rn(__fadd_rn(__fsub_rn(x2, x1), 1.0f),
                       __fadd_rn(__fsub_rn(y2, y1), 1.0f));
  }
  __syncthreads();
  const int i = blockIdx.x * 256 + t;
  if (i >= M) return;

  float bx1, by1, bx2, by2;
  if (i < N) {
    bx1 = all_rois[(size_t)i * 5 + 1];
    by1 = all_rois[(size_t)i * 5 + 2];
    bx2 = all_rois[(size_t)i * 5 + 3];
    by2 = all_rois[(size_t)i * 5 + 4];
  } else {
    int g = i - N;
    bx1 = sgx1[g]; by1 = sgy1[g]; bx2 = sgx2[g]; by2 = sgy2[g];
  }
  const float area = __fmul_rn(__fadd_rn(__fsub_rn(bx2, bx1), 1.0f),
                               __fadd_rn(__fsub_rn(by2, by1), 1.0f));
  float best = -1.0f;
  int bi = 0;
  for (int g = 0; g < G; ++g) {
    float ix1 = fmaxf(bx1, sgx1[g]);
    float iy1 = fmaxf(by1, sgy1[g]);
    float ix2 = fminf(bx2, sgx2[g]);
    float iy2 = fminf(by2, sgy2[g]);
    float iw = fmaxf(__fadd_rn(__fsub_rn(ix2, ix1), 1.0f), 0.0f);
    float ih = fmaxf(__fadd_rn(__fsub_rn(iy2, iy1), 1.0f), 0.0f);
    float inter = __fmul_rn(iw, ih);
    float uni = __fsub_rn(__fadd_rn(area, sga[g]), inter);
    float ov = __fdiv_rn(inter, uni);               // IEEE-rounded, matches XLA
    if (ov > best) { best = ov; bi = g; }           // first-max == jnp.argmax
  }

  // partitionable threefry: counter (hi=0, lo=i), output = x0 ^ x1
  uint32_t cx0 = 0u, cx1 = (uint32_t)i;
  threefry2x32(0u, 42u, cx0, cx1);
  uint32_t ubits = (cx0 ^ cx1) >> 9;                // mantissa of u in [0,1)

  uint32_t fg = (best >= 0.5f) ? 1u : 0u;
  uint32_t bg = (!fg && best >= 0.1f) ? 1u : 0u;
  score[i] = (ubits << 9) | ((uint32_t)bi << 2) | (fg << 1) | bg;
  if (fg)      atomicAdd(&hist[ubits >> 11], 1u);
  else if (bg) atomicAdd(&hist[NBINS + (ubits >> 11)], 1u);
}

// ---------------------------------------------------------------------------
// Kernel 2: compact with per-block redundant exact threshold.
// Each block computes Bth for both masks from the histogram (packed fg|bg
// uint64 suffix scan — logic verified in r4 Phase B), then filters its
// grid-stride slice of score[], appending candidates via global atomics.
// Bth<0 (mask count < TK): append ALL masked elements (=> cnt<TK signals
// fallback to final_kernel).
// ---------------------------------------------------------------------------
__global__ void __launch_bounds__(CBLOCK)
compact_kernel(const uint32_t* __restrict__ score, int M,
               const uint32_t* __restrict__ hist,
               int* __restrict__ meta_cnt,         // [cnt_fg, cnt_bg]
               uint64_t* __restrict__ cand) {
  __shared__ uint64_t gs[CBLOCK];
  __shared__ int s_jstar[2], s_bth[2];
  const int t = threadIdx.x;

  // --- exact per-mask threshold bin (redundant per block, no barrier) ---
  {
    const int b0 = 4 * t;
    uint64_t acc = 0;
    for (int k = 0; k < 4; ++k)
      acc += ((uint64_t)hist[b0 + k] << 32) | (uint64_t)hist[NBINS + b0 + k];
    gs[t] = acc;
    if (t < 2) s_jstar[t] = -1;
    __syncthreads();
    for (int d = 1; d < CBLOCK; d <<= 1) {
      uint64_t add = (t + d < CBLOCK) ? gs[t + d] : 0ull;
      __syncthreads();
      gs[t] += add;
      __syncthreads();
    }
    uint32_t vfg = (uint32_t)(gs[t] >> 32);
    uint32_t vbg = (uint32_t)gs[t];
    uint32_t nfg = (t < CBLOCK - 1) ? (uint32_t)(gs[t + 1] >> 32) : 0u;
    uint32_t nbg = (t < CBLOCK - 1) ? (uint32_t)gs[t + 1] : 0u;
    if (vfg >= (uint32_t)TK && (t == CBLOCK - 1 || nfg < (uint32_t)TK)) s_jstar[0] = t;
    if (vbg >= (uint32_t)TK && (t == CBLOCK - 1 || nbg < (uint32_t)TK)) s_jstar[1] = t;
    __syncthreads();
    if (t == 0) {
      for (int m = 0; m < 2; ++m) {
        int j = s_jstar[m], B = -1;
        if (j >= 0) {
          uint32_t base = 0;
          if (j < CBLOCK - 1)
            base = (m == 0) ? (uint32_t)(gs[j + 1] >> 32) : (uint32_t)gs[j + 1];
          const uint32_t* h = hist + m * NBINS;
          B = 4 * j;
          for (int b = 4 * j + 3; b >= 4 * j; --b) {
            base += h[b];
            if (base >= (uint32_t)TK) { B = b; break; }
          }
        }
        s_bth[m] = B;
      }
    }
    __syncthreads();
  }

  // --- filter + append ---
  for (int i = blockIdx.x * CBLOCK + t; i < M; i += CBLOCKS * CBLOCK) {
    uint32_t s = score[i];
    uint32_t mb = s & 3u;
    if (!mb) continue;
    int m = (mb & 2u) ? 0 : 1;
    int B = s_bth[m];
    if (B >= 0 && (int)(s >> 20) < B) continue;
    int p = atomicAdd(&meta_cnt[m], 1);
    if (p < CAND_MAX)
      cand[(size_t)m * CAND_MAX + p] =
          (((uint64_t)((s >> 9) + 1u)) << 32) | (uint64_t)(~(uint32_t)i);
  }
}

// ---------------------------------------------------------------------------
// Kernel 3 (verified r3): bitonic sort (key ((ubits+1)<<32)|~i == XLA stable
// top_k with where(mask,u,-1.0) padding) + fused finalize.
// Output layout: rois[256*5] | labels[256] | targets[256*84]
// ---------------------------------------------------------------------------
__global__ void __launch_bounds__(1024)
final_kernel(const float* __restrict__ all_rois,
             const float* __restrict__ gt_boxes,
             const int* __restrict__ gt_labels,
             const uint32_t* __restrict__ score,
             const uint64_t* __restrict__ cand_g,
             const int* __restrict__ meta_cnt,
             float* __restrict__ out, int N, int M) {
  __shared__ uint64_t cand[CAND_MAX];
  __shared__ int keep[2 * TK];
  __shared__ int fgvalid[TK];
  __shared__ float s_tx[2 * TK], s_ty[2 * TK], s_tw[2 * TK], s_th[2 * TK];
  __shared__ int s_label[2 * TK];
  const int t = threadIdx.x;

  for (int m = 0; m < 2; ++m) {
    int cnt = meta_cnt[m]; if (cnt > CAND_MAX) cnt = CAND_MAX;
    int P = TK;
    while (P < cnt) P <<= 1;
    for (int p = t; p < P; p += 1024)
      cand[p] = (p < cnt) ? cand_g[(size_t)m * CAND_MAX + p] : 0ull;
    __syncthreads();
    for (int k = 2; k <= P; k <<= 1) {
      for (int j = k >> 1; j > 0; j >>= 1) {
        for (int idx = t; idx < P; idx += 1024) {
          int l = idx ^ j;
          if (l > idx) {
            uint64_t a = cand[idx], b = cand[l];
            bool swp = ((idx & k) == 0) ? (a < b) : (a > b);
            if (swp) { cand[idx] = b; cand[l] = a; }
          }
        }
        __syncthreads();
      }
    }
    if (cnt < TK && t == 0) {       // mask had <TK members: pad with lowest-
      int fill = cnt;               // index non-masked (JAX -1.0 tie semantics)
      uint32_t mask_bit = (m == 0) ? 2u : 1u;
      for (int i = 0; i < M && fill < TK; ++i)
        if (!(score[i] & mask_bit)) cand[fill++] = (uint64_t)(~(uint32_t)i);
    }
    __syncthreads();
    if (t < TK) {
      uint64_t c = cand[t];
      keep[m * TK + t] = (int)(~(uint32_t)(c & 0xFFFFFFFFull));
      if (m == 0) fgvalid[t] = ((c >> 32) != 0ull) ? 1 : 0;
    }
    __syncthreads();
  }

  const int R = 2 * TK;
  float* rois_out   = out;
  float* labels_out = out + (size_t)R * 5;
  float* bt_out     = out + (size_t)R * 5 + R;

  if (t < R) {
    const int i = keep[t];
    float rimg, rx1, ry1, rx2, ry2;
    if (i < N) {
      rimg = all_rois[(size_t)i * 5 + 0];
      rx1  = all_rois[(size_t)i * 5 + 1];
      ry1  = all_rois[(size_t)i * 5 + 2];
      rx2  = all_rois[(size_t)i * 5 + 3];
      ry2  = all_rois[(size_t)i * 5 + 4];
    } else {
      int g = i - N;
      rimg = 0.0f;
      rx1 = gt_boxes[g * 4 + 0]; ry1 = gt_boxes[g * 4 + 1];
      rx2 = gt_boxes[g * 4 + 2]; ry2 = gt_boxes[g * 4 + 3];
    }
    rois_out[t * 5 + 0] = rimg;
    rois_out[t * 5 + 1] = rx1;
    rois_out[t * 5 + 2] = ry1;
    rois_out[t * 5 + 3] = rx2;
    rois_out[t * 5 + 4] = ry2;

    const int ga = (int)((score[i] >> 2) & 127u);
    int label = (t < TK && fgvalid[t]) ? gt_labels[ga] : 0;
    labels_out[t] = (float)label;
    s_label[t] = label;

    float gx1 = gt_boxes[ga * 4 + 0], gy1 = gt_boxes[ga * 4 + 1];
    float gx2 = gt_boxes[ga * 4 + 2], gy2 = gt_boxes[ga * 4 + 3];
    float ew = rx2 - rx1 + 1.0f, eh = ry2 - ry1 + 1.0f;
    float ecx = rx1 + 0.5f * ew, ecy = ry1 + 0.5f * eh;
    float gw = gx2 - gx1 + 1.0f, gh = gy2 - gy1 + 1.0f;
    float gcx = gx1 + 0.5f * gw, gcy = gy1 + 0.5f * gh;
    s_tx[t] = (gcx - ecx) / ew;
    s_ty[t] = (gcy - ecy) / eh;
    s_tw[t] = logf(gw / ew);
    s_th[t] = logf(gh / eh);
  }
  __syncthreads();

  const int TOT = R * 4 * NUM_CLASSES;
  for (int idx = t; idx < TOT; idx += 1024) {
    int r = idx / (4 * NUM_CLASSES);
    int c = idx - r * (4 * NUM_CLASSES);
    int lab = s_label[r];
    float v = 0.0f;
    if (lab > 0 && (c >> 2) == lab) {
      int cc = c & 3;
      v = (cc == 0) ? s_tx[r] : (cc == 1) ? s_ty[r] : (cc == 2) ? s_tw[r] : s_th[r];
    }
    bt_out[idx] = v;
  }
}

// ---------------------------------------------------------------------------
extern "C" void kernel_launch(void* const* d_in, const int* in_sizes, int n_in,
                              void* d_out, int out_size, void* d_ws, size_t ws_size,
                              hipStream_t stream) {
  const float* all_rois = (const float*)d_in[0];
  const float* gt_boxes = (const float*)d_in[1];
  const int*   gt_labels = (const int*)d_in[2];
  const int N = in_sizes[0] / 5;
  const int G = in_sizes[2];
  const int M = N + G;

  // workspace: [meta 256B][hist 32KB][score M*4][cand 64KB]
  char* ws = (char*)d_ws;
  int* meta = (int*)ws;                       // [0]=cnt_fg [1]=cnt_bg
  uint32_t* hist = (uint32_t*)(ws + 256);
  size_t off = 256 + (size_t)2 * NBINS * 4;
  uint32_t* score = (uint32_t*)(ws + off);
  off += (((size_t)M * 4) + 255) & ~(size_t)255;
  uint64_t* cand = (uint64_t*)(ws + off);
  float* out = (float*)d_out;

  hipMemsetAsync(ws, 0, 256 + (size_t)2 * NBINS * 4, stream);
  score_kernel<<<(M + 255) / 256, 256, 0, stream>>>(all_rois, gt_boxes, score,
                                                    hist, N, M, G);
  compact_kernel<<<CBLOCKS, CBLOCK, 0, stream>>>(score, M, hist, meta, cand);
  final_kernel<<<1, 1024, 0, stream>>>(all_rois, gt_boxes, gt_labels, score,
                                       cand, meta, out, N, M);
}